// Round 4
// baseline (446.683 us; speedup 1.0000x reference)
//
#include <hip/hip_runtime.h>

namespace {

constexpr int kB = 8;
constexpr int kCH = 256;
constexpr int kN = 2048;
constexpr int NSPLIT = 4;
constexpr int SLICE = kN / NSPLIT;  // 512 KV positions per block
constexpr int KVC = 64;             // chunk size
constexpr int NWAVE = 4;
constexpr int PS_STRIDE = KVC + 8;  // 72

constexpr float SCALE = 0.0625f;  // 256^-0.5
constexpr float LOG2E = 1.4426950408889634f;

typedef _Float16 f16x8 __attribute__((ext_vector_type(8)));
typedef _Float16 f16x4 __attribute__((ext_vector_type(4)));
typedef float f32x4 __attribute__((ext_vector_type(4)));

// ---------------------------------------------------------------------------
// Pre-pass: out[b][c][r] (f16) = in[b][r][c] (f32).  64x64 tiles, 4x4 register
// micro-transpose, no LDS. Reads 256B-coalesced; writes 32B segments (fine for
// a pre-pass that moves only 16MB).
__global__ void transpose_cvt(const float* __restrict__ in,
                              _Float16* __restrict__ out, int R, int C) {
  const int b = blockIdx.z;
  const int c0 = blockIdx.x * 64, r0 = blockIdx.y * 64;
  const int t = threadIdx.x;
  const float* ib = in + (size_t)b * R * C;
  _Float16* ob = out + (size_t)b * R * C;
  const int rr = (t >> 4) * 4, cc = (t & 15) * 4;
  const float* src = ib + (size_t)(r0 + rr) * C + c0 + cc;
  f32x4 v0 = *(const f32x4*)(src);
  f32x4 v1 = *(const f32x4*)(src + (size_t)C);
  f32x4 v2 = *(const f32x4*)(src + 2 * (size_t)C);
  f32x4 v3 = *(const f32x4*)(src + 3 * (size_t)C);
#pragma unroll
  for (int j = 0; j < 4; ++j) {
    f16x4 w;
    w[0] = (_Float16)v0[j]; w[1] = (_Float16)v1[j];
    w[2] = (_Float16)v2[j]; w[3] = (_Float16)v3[j];
    *(f16x4*)(ob + (size_t)(c0 + cc + j) * R + r0 + rr) = w;
  }
}

// ---------------------------------------------------------------------------
// Main: flash-attention partial over a 512-pos KV slice for 64 Q rows.
// No KV LDS staging: fragments load from L2/L1-resident f16 kt/vt directly.
// Partials: pacc[b][g][c][n] f16 (unnormalized O^T), pm/pl[b][n][g] f32.
__global__ __launch_bounds__(256, 3) void attn_part(
    const _Float16* __restrict__ kt, const float* __restrict__ qg,
    const _Float16* __restrict__ vt, _Float16* __restrict__ pacc,
    float* __restrict__ pm, float* __restrict__ pl)
{
  __shared__ alignas(16) _Float16 Ps[NWAVE][16][PS_STRIDE];
  __shared__ float red[NWAVE][16];

  const int tid = threadIdx.x;
  const int wv = tid >> 6;
  const int lane = tid & 63;
  const int s = lane & 15;
  const int qd = lane >> 4;

  // bid&31 -> (b,g): all 32 q-tile blocks of one KV slice share an XCD.
  const int bg = blockIdx.x & 31;
  const int qt = blockIdx.x >> 5;
  const int b = bg >> 2, g = bg & 3;
  const int n0w = qt * 64 + wv * 16;
  const int kvb = g * SLICE;

  const _Float16* ktb = kt + (size_t)b * kN * kCH;
  const _Float16* vtb = vt + (size_t)b * kCH * kN;
  const float* qb = qg + (size_t)b * kN * kCH;

  // Q fragments: qf[ks][j] = Q[n0w+s][ks*32 + qd*8 + j]
  f16x8 qf[8];
  {
    const float* qrow = qb + (size_t)(n0w + s) * kCH + qd * 8;
#pragma unroll
    for (int ks = 0; ks < 8; ++ks) {
      f32x4 a = *(const f32x4*)(qrow + ks * 32);
      f32x4 c = *(const f32x4*)(qrow + ks * 32 + 4);
      f16x8 h;
      h[0] = (_Float16)a[0]; h[1] = (_Float16)a[1];
      h[2] = (_Float16)a[2]; h[3] = (_Float16)a[3];
      h[4] = (_Float16)c[0]; h[5] = (_Float16)c[1];
      h[6] = (_Float16)c[2]; h[7] = (_Float16)c[3];
      qf[ks] = h;
    }
  }

  f32x4 acc[16];
#pragma unroll
  for (int i = 0; i < 16; ++i) acc[i] = f32x4{0.f, 0.f, 0.f, 0.f};
  float m_r[4] = {-1e30f, -1e30f, -1e30f, -1e30f};
  float l_r[4] = {0.f, 0.f, 0.f, 0.f};

  for (int ck = 0; ck < SLICE / KVC; ++ck) {
    const int kv0 = kvb + ck * KVC;
    __syncthreads();  // loose lockstep: 4 waves read identical K/V frags -> L1

    // ---- QK^T
    f32x4 sacc[4];
#pragma unroll
    for (int mc = 0; mc < 4; ++mc) sacc[mc] = f32x4{0.f, 0.f, 0.f, 0.f};
#pragma unroll
    for (int mc = 0; mc < 4; ++mc) {
      const _Float16* kp = ktb + (size_t)(kv0 + mc * 16 + s) * kCH + qd * 8;
#pragma unroll
      for (int ks = 0; ks < 8; ++ks) {
        f16x8 bf = *(const f16x8*)(kp + ks * 32);
        sacc[mc] = __builtin_amdgcn_mfma_f32_16x16x32_f16(qf[ks], bf, sacc[mc], 0, 0, 0);
      }
    }

    // ---- online softmax (rows qd*4+r, cols mc*16+s)
    float pmax[4];
#pragma unroll
    for (int r = 0; r < 4; ++r)
      pmax[r] = fmaxf(fmaxf(sacc[0][r], sacc[1][r]), fmaxf(sacc[2][r], sacc[3][r]));
#pragma unroll
    for (int off = 1; off < 16; off <<= 1) {
#pragma unroll
      for (int r = 0; r < 4; ++r)
        pmax[r] = fmaxf(pmax[r], __shfl_xor(pmax[r], off, 64));
    }
    float corr[4], lsum[4];
#pragma unroll
    for (int r = 0; r < 4; ++r) {
      float mn = fmaxf(m_r[r], SCALE * pmax[r]);
      corr[r] = exp2f((m_r[r] - mn) * LOG2E);
      m_r[r] = mn;
      lsum[r] = 0.f;
    }
#pragma unroll
    for (int mc = 0; mc < 4; ++mc) {
#pragma unroll
      for (int r = 0; r < 4; ++r) {
        float pvf = exp2f((SCALE * sacc[mc][r] - m_r[r]) * LOG2E);
        lsum[r] += pvf;
        Ps[wv][qd * 4 + r][mc * 16 + s] = (_Float16)pvf;
      }
    }
#pragma unroll
    for (int off = 1; off < 16; off <<= 1) {
#pragma unroll
      for (int r = 0; r < 4; ++r) lsum[r] += __shfl_xor(lsum[r], off, 64);
    }
#pragma unroll
    for (int r = 0; r < 4; ++r) l_r[r] = l_r[r] * corr[r] + lsum[r];

    if (s == 0) {
#pragma unroll
      for (int r = 0; r < 4; ++r) red[wv][qd * 4 + r] = corr[r];
    }
    asm volatile("s_waitcnt lgkmcnt(0)" ::: "memory");
    const float sc = red[wv][s];
#pragma unroll
    for (int i = 0; i < 16; ++i) acc[i] *= sc;

    // ---- PV: O^T += V^T @ P^T  (A = vt frags from global, B = P from LDS)
#pragma unroll
    for (int ms = 0; ms < 2; ++ms) {
      f16x8 pf = *(const f16x8*)(&Ps[wv][s][ms * 32 + qd * 8]);
      const _Float16* vp = vtb + (size_t)s * kN + kv0 + ms * 32 + qd * 8;
#pragma unroll
      for (int ct = 0; ct < 16; ++ct) {
        f16x8 vf = *(const f16x8*)(vp + (size_t)ct * 16 * kN);
        acc[ct] = __builtin_amdgcn_mfma_f32_16x16x32_f16(vf, pf, acc[ct], 0, 0, 0);
      }
    }
  }

  // ---- store partials (unnormalized)
  _Float16* pb = pacc + (size_t)(b * NSPLIT + g) * kCH * kN;
#pragma unroll
  for (int ct = 0; ct < 16; ++ct) {
#pragma unroll
    for (int r = 0; r < 4; ++r) {
      const int c = ct * 16 + qd * 4 + r;
      pb[(size_t)c * kN + n0w + s] = (_Float16)acc[ct][r];
    }
  }
  if (s == 0) {
#pragma unroll
    for (int r = 0; r < 4; ++r) {
      const int n = n0w + qd * 4 + r;
      pm[((size_t)b * kN + n) * NSPLIT + g] = m_r[r];
      pl[((size_t)b * kN + n) * NSPLIT + g] = l_r[r];
    }
  }
}

// ---------------------------------------------------------------------------
// Merge: out[b][c][n] = sum_g a_g * pacc[b][g][c][n] / L,  a_g = e^{m_g-M}.
// grid (kN/256, kCH/16, kB), block 256: thread = one c-row x 16 n.
__global__ void attn_merge(const _Float16* __restrict__ pacc,
                           const float* __restrict__ pm,
                           const float* __restrict__ pl,
                           float* __restrict__ out) {
  const int b = blockIdx.z;
  const int c = blockIdx.y * 16 + (threadIdx.x >> 4);
  const int nn0 = blockIdx.x * 256 + (threadIdx.x & 15) * 16;

  f16x8 dA[NSPLIT], dB[NSPLIT];
#pragma unroll
  for (int g = 0; g < NSPLIT; ++g) {
    const _Float16* p = pacc + ((size_t)(b * NSPLIT + g) * kCH + c) * kN + nn0;
    dA[g] = *(const f16x8*)(p);
    dB[g] = *(const f16x8*)(p + 8);
  }
  float res[16];
#pragma unroll
  for (int j = 0; j < 16; ++j) {
    const int n = nn0 + j;
    f32x4 m4 = *(const f32x4*)(pm + ((size_t)b * kN + n) * NSPLIT);
    f32x4 l4 = *(const f32x4*)(pl + ((size_t)b * kN + n) * NSPLIT);
    float M = fmaxf(fmaxf(m4[0], m4[1]), fmaxf(m4[2], m4[3]));
    float a0 = exp2f((m4[0] - M) * LOG2E);
    float a1 = exp2f((m4[1] - M) * LOG2E);
    float a2 = exp2f((m4[2] - M) * LOG2E);
    float a3 = exp2f((m4[3] - M) * LOG2E);
    float L = a0 * l4[0] + a1 * l4[1] + a2 * l4[2] + a3 * l4[3];
    float v;
    if (j < 8)
      v = a0 * (float)dA[0][j] + a1 * (float)dA[1][j] +
          a2 * (float)dA[2][j] + a3 * (float)dA[3][j];
    else
      v = a0 * (float)dB[0][j - 8] + a1 * (float)dB[1][j - 8] +
          a2 * (float)dB[2][j - 8] + a3 * (float)dB[3][j - 8];
    res[j] = v / L;
  }
  float* o = out + ((size_t)b * kCH + c) * kN + nn0;
#pragma unroll
  for (int j = 0; j < 4; ++j)
    *(f32x4*)(o + j * 4) = f32x4{res[j * 4], res[j * 4 + 1], res[j * 4 + 2], res[j * 4 + 3]};
}

// ---------------------------------------------------------------------------
// Round-1 fallback (used only if ws_size is too small). Verified correct.
constexpr int QBLK_FB = 64;
constexpr int KVBLK_FB = 64;
constexpr int KS_STRIDE_FB = kCH + 8;
constexpr int VS_STRIDE_FB = KVBLK_FB + 8;

__global__ __launch_bounds__(256, 1) void attn_fwd_fb(
    const float* __restrict__ kg, const float* __restrict__ qg,
    const float* __restrict__ vg, float* __restrict__ og)
{
  __shared__ alignas(16) _Float16 Ks[KVBLK_FB][KS_STRIDE_FB];
  __shared__ alignas(16) _Float16 Vs[kCH][VS_STRIDE_FB];
  __shared__ alignas(16) _Float16 Psf[NWAVE][16][VS_STRIDE_FB];
  __shared__ float red[NWAVE][16];

  const int tid = threadIdx.x;
  const int wv = tid >> 6, lane = tid & 63, s = lane & 15, qd = lane >> 4;
  const int b = blockIdx.x & 7, qt = blockIdx.x >> 3;
  const int n0w = qt * QBLK_FB + wv * 16;
  const float* kb = kg + (size_t)b * kCH * kN;
  const float* qb = qg + (size_t)b * kN * kCH;
  const float* vb = vg + (size_t)b * kN * kCH;
  float* ob = og + (size_t)b * kCH * kN;

  f16x8 qf[8];
  {
    const float* qrow = qb + (size_t)(n0w + s) * kCH + qd * 8;
#pragma unroll
    for (int ks = 0; ks < 8; ++ks) {
      f32x4 a = *(const f32x4*)(qrow + ks * 32);
      f32x4 c = *(const f32x4*)(qrow + ks * 32 + 4);
      f16x8 h;
      h[0] = (_Float16)a[0]; h[1] = (_Float16)a[1];
      h[2] = (_Float16)a[2]; h[3] = (_Float16)a[3];
      h[4] = (_Float16)c[0]; h[5] = (_Float16)c[1];
      h[6] = (_Float16)c[2]; h[7] = (_Float16)c[3];
      qf[ks] = h;
    }
  }
  f32x4 acc[16];
#pragma unroll
  for (int i = 0; i < 16; ++i) acc[i] = f32x4{0.f, 0.f, 0.f, 0.f};
  float m_r[4] = {-1e30f, -1e30f, -1e30f, -1e30f};
  float l_r[4] = {0.f, 0.f, 0.f, 0.f};

  for (int kv0 = 0; kv0 < kN; kv0 += KVBLK_FB) {
    __syncthreads();
    {
      const int m0 = 4 * (tid >> 4), c0b = 4 * (tid & 15);
#pragma unroll
      for (int p = 0; p < 4; ++p) {
        const int c0 = c0b + 64 * p;
        const float* src = kb + (size_t)c0 * kN + kv0 + m0;
        f32x4 r0 = *(const f32x4*)(src);
        f32x4 r1 = *(const f32x4*)(src + kN);
        f32x4 r2 = *(const f32x4*)(src + 2 * kN);
        f32x4 r3 = *(const f32x4*)(src + 3 * kN);
#pragma unroll
        for (int i = 0; i < 4; ++i) {
          f16x4 w;
          w[0] = (_Float16)r0[i]; w[1] = (_Float16)r1[i];
          w[2] = (_Float16)r2[i]; w[3] = (_Float16)r3[i];
          *(f16x4*)(&Ks[m0 + i][c0]) = w;
        }
      }
    }
    {
      const int m0 = 4 * (tid & 15), c0b = 4 * (tid >> 4);
#pragma unroll
      for (int p = 0; p < 4; ++p) {
        const int c0 = c0b + 64 * p;
        const float* src = vb + (size_t)(kv0 + m0) * kCH + c0;
        f32x4 r0 = *(const f32x4*)(src);
        f32x4 r1 = *(const f32x4*)(src + kCH);
        f32x4 r2 = *(const f32x4*)(src + 2 * kCH);
        f32x4 r3 = *(const f32x4*)(src + 3 * kCH);
#pragma unroll
        for (int i = 0; i < 4; ++i) {
          f16x4 w;
          w[0] = (_Float16)r0[i]; w[1] = (_Float16)r1[i];
          w[2] = (_Float16)r2[i]; w[3] = (_Float16)r3[i];
          *(f16x4*)(&Vs[c0 + i][m0]) = w;
        }
      }
    }
    __syncthreads();

    f32x4 sacc[4];
#pragma unroll
    for (int mc = 0; mc < 4; ++mc) sacc[mc] = f32x4{0.f, 0.f, 0.f, 0.f};
#pragma unroll
    for (int mc = 0; mc < 4; ++mc) {
#pragma unroll
      for (int ks = 0; ks < 8; ++ks) {
        f16x8 bf = *(const f16x8*)(&Ks[mc * 16 + s][ks * 32 + qd * 8]);
        sacc[mc] = __builtin_amdgcn_mfma_f32_16x16x32_f16(qf[ks], bf, sacc[mc], 0, 0, 0);
      }
    }
    float pmax[4];
#pragma unroll
    for (int r = 0; r < 4; ++r)
      pmax[r] = fmaxf(fmaxf(sacc[0][r], sacc[1][r]), fmaxf(sacc[2][r], sacc[3][r]));
#pragma unroll
    for (int off = 1; off < 16; off <<= 1) {
#pragma unroll
      for (int r = 0; r < 4; ++r)
        pmax[r] = fmaxf(pmax[r], __shfl_xor(pmax[r], off, 64));
    }
    float corr[4], lsum[4];
#pragma unroll
    for (int r = 0; r < 4; ++r) {
      float mn = fmaxf(m_r[r], SCALE * pmax[r]);
      corr[r] = exp2f((m_r[r] - mn) * LOG2E);
      m_r[r] = mn;
      lsum[r] = 0.f;
    }
#pragma unroll
    for (int mc = 0; mc < 4; ++mc) {
#pragma unroll
      for (int r = 0; r < 4; ++r) {
        float pvf = exp2f((SCALE * sacc[mc][r] - m_r[r]) * LOG2E);
        lsum[r] += pvf;
        Psf[wv][qd * 4 + r][mc * 16 + s] = (_Float16)pvf;
      }
    }
#pragma unroll
    for (int off = 1; off < 16; off <<= 1) {
#pragma unroll
      for (int r = 0; r < 4; ++r) lsum[r] += __shfl_xor(lsum[r], off, 64);
    }
#pragma unroll
    for (int r = 0; r < 4; ++r) l_r[r] = l_r[r] * corr[r] + lsum[r];
    if (s == 0) {
#pragma unroll
      for (int r = 0; r < 4; ++r) red[wv][qd * 4 + r] = corr[r];
    }
    asm volatile("s_waitcnt lgkmcnt(0)" ::: "memory");
    const float sc = red[wv][s];
#pragma unroll
    for (int i = 0; i < 16; ++i) acc[i] *= sc;
#pragma unroll
    for (int ms = 0; ms < 2; ++ms) {
      f16x8 pf = *(const f16x8*)(&Psf[wv][s][ms * 32 + qd * 8]);
#pragma unroll
      for (int ct = 0; ct < 16; ++ct) {
        f16x8 vf = *(const f16x8*)(&Vs[ct * 16 + s][ms * 32 + qd * 8]);
        acc[ct] = __builtin_amdgcn_mfma_f32_16x16x32_f16(vf, pf, acc[ct], 0, 0, 0);
      }
    }
  }
  if (s == 0) {
#pragma unroll
    for (int r = 0; r < 4; ++r) red[wv][qd * 4 + r] = 1.0f / l_r[r];
  }
  asm volatile("s_waitcnt lgkmcnt(0)" ::: "memory");
  const float inv = red[wv][s];
#pragma unroll
  for (int ct = 0; ct < 16; ++ct) {
#pragma unroll
    for (int r = 0; r < 4; ++r) {
      const int c = ct * 16 + qd * 4 + r;
      ob[(size_t)c * kN + n0w + s] = acc[ct][r] * inv;
    }
  }
}

constexpr size_t KT_ELEMS = (size_t)kB * kN * kCH;             // 4M f16
constexpr size_t PACC_ELEMS = (size_t)NSPLIT * kB * kCH * kN;  // 16M f16
constexpr size_t PM_ELEMS = (size_t)kB * kN * NSPLIT;          // 64K f32
constexpr size_t WS_NEED =
    (2 * KT_ELEMS + PACC_ELEMS) * sizeof(_Float16) + 2 * PM_ELEMS * sizeof(float);

}  // namespace

extern "C" void kernel_launch(void* const* d_in, const int* in_sizes, int n_in,
                              void* d_out, int out_size, void* d_ws, size_t ws_size,
                              hipStream_t stream) {
  (void)in_sizes; (void)n_in; (void)out_size;
  const float* k = (const float*)d_in[0];
  const float* q = (const float*)d_in[1];
  const float* v = (const float*)d_in[2];
  float* out = (float*)d_out;

  if (ws_size < WS_NEED) {
    hipLaunchKernelGGL(attn_fwd_fb, dim3(kB * (kN / QBLK_FB)), dim3(256), 0, stream,
                       k, q, v, out);
    return;
  }

  _Float16* kt = (_Float16*)d_ws;
  _Float16* vt = kt + KT_ELEMS;
  _Float16* pacc = vt + KT_ELEMS;
  float* pm = (float*)(pacc + PACC_ELEMS);
  float* pl = pm + PM_ELEMS;

  // kt[b][n][c] = k[b][c][n];  vt[b][c][n] = v[b][n][c]
  hipLaunchKernelGGL(transpose_cvt, dim3(kN / 64, kCH / 64, kB), dim3(256), 0, stream,
                     k, kt, kCH, kN);
  hipLaunchKernelGGL(transpose_cvt, dim3(kCH / 64, kN / 64, kB), dim3(256), 0, stream,
                     v, vt, kN, kCH);
  hipLaunchKernelGGL(attn_part, dim3(kB * (kN / 64) * NSPLIT), dim3(256), 0, stream,
                     kt, q, vt, pacc, pm, pl);
  hipLaunchKernelGGL(attn_merge, dim3(kN / 256, kCH / 16, kB), dim3(256), 0, stream,
                     pacc, pm, pl, out);
}

// Round 5
// 178.751 us; speedup vs baseline: 2.4989x; 2.4989x over previous
//
#include <hip/hip_runtime.h>

namespace {

constexpr int kB = 8;
constexpr int kCH = 256;
constexpr int kN = 2048;
constexpr int NSPLIT = 2;
constexpr int SLICE = kN / NSPLIT;  // 1024 KV positions per block
constexpr int KVC = 64;
constexpr int NWAVE = 4;
constexpr int PS_STRIDE = KVC + 8;  // 72

constexpr float SCALE = 0.0625f;  // 256^-0.5
constexpr float LOG2E = 1.4426950408889634f;

typedef _Float16 f16x8 __attribute__((ext_vector_type(8)));
typedef _Float16 f16x4 __attribute__((ext_vector_type(4)));
typedef float f32x4 __attribute__((ext_vector_type(4)));

__device__ __forceinline__ void gload_lds16(const void* g, void* l) {
  __builtin_amdgcn_global_load_lds(
      (const __attribute__((address_space(1))) void*)g,
      (__attribute__((address_space(3))) void*)l, 16, 0, 0);
}

// ---------------------------------------------------------------------------
// LDS transpose pre-pass: out[b][c][r] (f16) = in[b][r][c] (f32).
// 64x64 tile; coalesced 64B-group reads AND 128B-contiguous writes.
__global__ __launch_bounds__(256) void transpose_cvt2(
    const float* __restrict__ in, _Float16* __restrict__ out, int R, int C) {
  __shared__ _Float16 T[64][72];
  const int b = blockIdx.z;
  const int r0 = blockIdx.y * 64, c0 = blockIdx.x * 64;
  const int t = threadIdx.x;

  const float* ib =
      in + (size_t)b * R * C + (size_t)(r0 + (t >> 2)) * C + c0 + (t & 3) * 4;
#pragma unroll
  for (int q = 0; q < 4; ++q) {
    f32x4 v = *(const f32x4*)(ib + q * 16);
    f16x4 w;
    w[0] = (_Float16)v[0]; w[1] = (_Float16)v[1];
    w[2] = (_Float16)v[2]; w[3] = (_Float16)v[3];
    *(f16x4*)(&T[t >> 2][(t & 3) * 4 + q * 16]) = w;
  }
  __syncthreads();
  const int cl = t >> 2, ch = t & 3;
  f16x8 o0, o1;
#pragma unroll
  for (int j = 0; j < 8; ++j) o0[j] = T[ch * 16 + j][cl];
#pragma unroll
  for (int j = 0; j < 8; ++j) o1[j] = T[ch * 16 + 8 + j][cl];
  _Float16* ob = out + (size_t)b * R * C + (size_t)(c0 + cl) * R + r0 + ch * 16;
  *(f16x8*)(ob) = o0;
  *(f16x8*)(ob + 8) = o1;
}

// ---------------------------------------------------------------------------
// Flash-attention partial over a 1024-pos KV slice for 64 Q rows.
// K/V tiles staged to LDS via global_load_lds (16B, zero-VGPR) with the
// XOR-swizzle baked into the per-lane GLOBAL source address (LDS dest stays
// linear); ds_read_b128 fragments apply the same XOR -> 2-way conflicts only.
__global__ __launch_bounds__(256, 2) void attn_part(
    const _Float16* __restrict__ kt, const float* __restrict__ qg,
    const _Float16* __restrict__ vt, _Float16* __restrict__ pacc,
    float* __restrict__ pm, float* __restrict__ pl)
{
  __shared__ alignas(16) char KsB[64 * 512];   // swizzled [m][cByte], 32KB
  __shared__ alignas(16) char VsB[256 * 128];  // swizzled [c][mByte], 32KB
  __shared__ alignas(16) _Float16 Ps[NWAVE][16][PS_STRIDE];
  __shared__ float red[NWAVE][16];

  const int tid = threadIdx.x;
  const int wv = tid >> 6;
  const int lane = tid & 63;
  const int s = lane & 15;
  const int qd = lane >> 4;
  const int sw = (s & 7) << 4;  // XOR swizzle key (bits 4-6)
  const int qd16 = qd << 4;

  const int bg = blockIdx.x & 15;  // (b,g): slice pinned per-XCD
  const int qt = blockIdx.x >> 4;
  const int b = bg >> 1, g = bg & 1;
  const int n0w = qt * 64 + wv * 16;
  const int kvb = g * SLICE;

  const char* ktB = (const char*)(kt + (size_t)b * kN * kCH);
  const char* vtB = (const char*)(vt + (size_t)b * kCH * kN);
  const float* qb = qg + (size_t)b * kN * kCH;

  // Q fragments: qf[ks][j] = Q[n0w+s][ks*32 + qd*8 + j]
  f16x8 qf[8];
  {
    const float* qrow = qb + (size_t)(n0w + s) * kCH + qd * 8;
#pragma unroll
    for (int ks = 0; ks < 8; ++ks) {
      f32x4 a = *(const f32x4*)(qrow + ks * 32);
      f32x4 c = *(const f32x4*)(qrow + ks * 32 + 4);
      f16x8 h;
      h[0] = (_Float16)a[0]; h[1] = (_Float16)a[1];
      h[2] = (_Float16)a[2]; h[3] = (_Float16)a[3];
      h[4] = (_Float16)c[0]; h[5] = (_Float16)c[1];
      h[6] = (_Float16)c[2]; h[7] = (_Float16)c[3];
      qf[ks] = h;
    }
  }

  f32x4 acc[16];
#pragma unroll
  for (int i = 0; i < 16; ++i) acc[i] = f32x4{0.f, 0.f, 0.f, 0.f};
  float m_r[4] = {-1e30f, -1e30f, -1e30f, -1e30f};
  float l_r[4] = {0.f, 0.f, 0.f, 0.f};

  for (int ck = 0; ck < SLICE / KVC; ++ck) {
    const int kv0 = kvb + ck * KVC;
    __syncthreads();  // prev tile reads done before overwrite

    // ---- stage K (32KB) + V (32KB): 8+8 wave-issues of 1KB each
    {
      const char* kSrc = ktB + (size_t)kv0 * 512;  // row m: 512B (kCH f16)
      const char* vSrc = vtB + (size_t)kv0 * 2;    // row c: stride kN*2=4096B
#pragma unroll
      for (int ii = 0; ii < 8; ++ii) {
        const int j = ii * 4 + wv;
        const int L = j * 1024 + lane * 16;
        {  // K: row = L>>9 (2 rows / issue)
          const int row = L >> 9, cb = L & 511;
          gload_lds16(kSrc + (size_t)(row << 9) + (cb ^ ((row & 7) << 4)),
                      KsB + j * 1024);
        }
        {  // V: row = L>>7 (8 rows / issue)
          const int row = L >> 7, cb = L & 127;
          gload_lds16(vSrc + (size_t)row * 4096 + (cb ^ ((row & 7) << 4)),
                      VsB + j * 1024);
        }
      }
    }
    __syncthreads();

    // ---- QK^T: S[16n x 64m], A=Q(reg), B=K(LDS swizzled)
    f32x4 sacc[4];
#pragma unroll
    for (int mc = 0; mc < 4; ++mc) sacc[mc] = f32x4{0.f, 0.f, 0.f, 0.f};
#pragma unroll
    for (int mc = 0; mc < 4; ++mc) {
      const char* kr = KsB + (mc * 16 + s) * 512;
#pragma unroll
      for (int ks = 0; ks < 8; ++ks) {
        f16x8 bf = *(const f16x8*)(kr + (((ks << 6) | qd16) ^ sw));
        sacc[mc] = __builtin_amdgcn_mfma_f32_16x16x32_f16(qf[ks], bf, sacc[mc], 0, 0, 0);
      }
    }

    // ---- online softmax (rows qd*4+r, cols mc*16+s)
    float pmax[4];
#pragma unroll
    for (int r = 0; r < 4; ++r)
      pmax[r] = fmaxf(fmaxf(sacc[0][r], sacc[1][r]), fmaxf(sacc[2][r], sacc[3][r]));
#pragma unroll
    for (int off = 1; off < 16; off <<= 1) {
#pragma unroll
      for (int r = 0; r < 4; ++r)
        pmax[r] = fmaxf(pmax[r], __shfl_xor(pmax[r], off, 64));
    }
    float corr[4], lsum[4];
#pragma unroll
    for (int r = 0; r < 4; ++r) {
      float mn = fmaxf(m_r[r], SCALE * pmax[r]);
      corr[r] = exp2f((m_r[r] - mn) * LOG2E);
      m_r[r] = mn;
      lsum[r] = 0.f;
    }
#pragma unroll
    for (int mc = 0; mc < 4; ++mc) {
#pragma unroll
      for (int r = 0; r < 4; ++r) {
        float pvf = exp2f((SCALE * sacc[mc][r] - m_r[r]) * LOG2E);
        lsum[r] += pvf;
        Ps[wv][qd * 4 + r][mc * 16 + s] = (_Float16)pvf;
      }
    }
#pragma unroll
    for (int off = 1; off < 16; off <<= 1) {
#pragma unroll
      for (int r = 0; r < 4; ++r) lsum[r] += __shfl_xor(lsum[r], off, 64);
    }
#pragma unroll
    for (int r = 0; r < 4; ++r) l_r[r] = l_r[r] * corr[r] + lsum[r];

    if (s == 0) {
#pragma unroll
      for (int r = 0; r < 4; ++r) red[wv][qd * 4 + r] = corr[r];
    }
    asm volatile("s_waitcnt lgkmcnt(0)" ::: "memory");
    const float sc = red[wv][s];
#pragma unroll
    for (int i = 0; i < 16; ++i) acc[i] *= sc;

    // ---- PV: O^T += V^T @ P^T  (A=V from LDS swizzled, B=P from LDS)
#pragma unroll
    for (int ms = 0; ms < 2; ++ms) {
      f16x8 pf = *(const f16x8*)(&Ps[wv][s][ms * 32 + qd * 8]);
#pragma unroll
      for (int ct = 0; ct < 16; ++ct) {
        const char* vr = VsB + (ct * 16 + s) * 128;
        f16x8 vf = *(const f16x8*)(vr + (((ms << 6) | qd16) ^ sw));
        acc[ct] = __builtin_amdgcn_mfma_f32_16x16x32_f16(vf, pf, acc[ct], 0, 0, 0);
      }
    }
  }

  // ---- store partials (unnormalized)
  _Float16* pb = pacc + (size_t)(b * NSPLIT + g) * kCH * kN;
#pragma unroll
  for (int ct = 0; ct < 16; ++ct) {
#pragma unroll
    for (int r = 0; r < 4; ++r) {
      const int c = ct * 16 + qd * 4 + r;
      pb[(size_t)c * kN + n0w + s] = (_Float16)acc[ct][r];
    }
  }
  if (s == 0) {
#pragma unroll
    for (int r = 0; r < 4; ++r) {
      const int n = n0w + qd * 4 + r;
      pm[((size_t)b * kN + n) * NSPLIT + g] = m_r[r];
      pl[((size_t)b * kN + n) * NSPLIT + g] = l_r[r];
    }
  }
}

// ---------------------------------------------------------------------------
// Merge: out[b][c][n] = sum_g a_g * pacc[b][g][c][n] / L.  pm/pl loads are
// 128B-contiguous per thread (coalesced), not per-j gathers.
__global__ void attn_merge(const _Float16* __restrict__ pacc,
                           const float* __restrict__ pm,
                           const float* __restrict__ pl,
                           float* __restrict__ out) {
  const int b = blockIdx.z;
  const int c = blockIdx.y * 16 + (threadIdx.x >> 4);
  const int nn0 = blockIdx.x * 256 + (threadIdx.x & 15) * 16;

  f16x8 dA[NSPLIT], dB[NSPLIT];
#pragma unroll
  for (int g = 0; g < NSPLIT; ++g) {
    const _Float16* p = pacc + ((size_t)(b * NSPLIT + g) * kCH + c) * kN + nn0;
    dA[g] = *(const f16x8*)(p);
    dB[g] = *(const f16x8*)(p + 8);
  }
  float mv[32], lv[32];
  const float* pmB = pm + ((size_t)b * kN + nn0) * NSPLIT;
  const float* plB = pl + ((size_t)b * kN + nn0) * NSPLIT;
#pragma unroll
  for (int q = 0; q < 8; ++q) {
    *(f32x4*)&mv[q * 4] = *(const f32x4*)(pmB + q * 4);
    *(f32x4*)&lv[q * 4] = *(const f32x4*)(plB + q * 4);
  }
  float res[16];
#pragma unroll
  for (int j = 0; j < 16; ++j) {
    float m0 = mv[2 * j], m1 = mv[2 * j + 1];
    float M = fmaxf(m0, m1);
    float a0 = exp2f((m0 - M) * LOG2E);
    float a1 = exp2f((m1 - M) * LOG2E);
    float L = a0 * lv[2 * j] + a1 * lv[2 * j + 1];
    float v = (j < 8) ? a0 * (float)dA[0][j] + a1 * (float)dA[1][j]
                      : a0 * (float)dB[0][j - 8] + a1 * (float)dB[1][j - 8];
    res[j] = v / L;
  }
  float* o = out + ((size_t)b * kCH + c) * kN + nn0;
#pragma unroll
  for (int j = 0; j < 4; ++j)
    *(f32x4*)(o + j * 4) = f32x4{res[j * 4], res[j * 4 + 1], res[j * 4 + 2], res[j * 4 + 3]};
}

// ---------------------------------------------------------------------------
// Round-1 fallback (used only if ws_size is too small). Verified correct.
constexpr int QBLK_FB = 64;
constexpr int KVBLK_FB = 64;
constexpr int KS_STRIDE_FB = kCH + 8;
constexpr int VS_STRIDE_FB = KVBLK_FB + 8;

__global__ __launch_bounds__(256, 1) void attn_fwd_fb(
    const float* __restrict__ kg, const float* __restrict__ qg,
    const float* __restrict__ vg, float* __restrict__ og)
{
  __shared__ alignas(16) _Float16 Ks[KVBLK_FB][KS_STRIDE_FB];
  __shared__ alignas(16) _Float16 Vs[kCH][VS_STRIDE_FB];
  __shared__ alignas(16) _Float16 Psf[NWAVE][16][VS_STRIDE_FB];
  __shared__ float red[NWAVE][16];

  const int tid = threadIdx.x;
  const int wv = tid >> 6, lane = tid & 63, s = lane & 15, qd = lane >> 4;
  const int b = blockIdx.x & 7, qt = blockIdx.x >> 3;
  const int n0w = qt * QBLK_FB + wv * 16;
  const float* kb = kg + (size_t)b * kCH * kN;
  const float* qb = qg + (size_t)b * kN * kCH;
  const float* vb = vg + (size_t)b * kN * kCH;
  float* ob = og + (size_t)b * kCH * kN;

  f16x8 qf[8];
  {
    const float* qrow = qb + (size_t)(n0w + s) * kCH + qd * 8;
#pragma unroll
    for (int ks = 0; ks < 8; ++ks) {
      f32x4 a = *(const f32x4*)(qrow + ks * 32);
      f32x4 c = *(const f32x4*)(qrow + ks * 32 + 4);
      f16x8 h;
      h[0] = (_Float16)a[0]; h[1] = (_Float16)a[1];
      h[2] = (_Float16)a[2]; h[3] = (_Float16)a[3];
      h[4] = (_Float16)c[0]; h[5] = (_Float16)c[1];
      h[6] = (_Float16)c[2]; h[7] = (_Float16)c[3];
      qf[ks] = h;
    }
  }
  f32x4 acc[16];
#pragma unroll
  for (int i = 0; i < 16; ++i) acc[i] = f32x4{0.f, 0.f, 0.f, 0.f};
  float m_r[4] = {-1e30f, -1e30f, -1e30f, -1e30f};
  float l_r[4] = {0.f, 0.f, 0.f, 0.f};

  for (int kv0 = 0; kv0 < kN; kv0 += KVBLK_FB) {
    __syncthreads();
    {
      const int m0 = 4 * (tid >> 4), c0b = 4 * (tid & 15);
#pragma unroll
      for (int p = 0; p < 4; ++p) {
        const int c0 = c0b + 64 * p;
        const float* src = kb + (size_t)c0 * kN + kv0 + m0;
        f32x4 r0 = *(const f32x4*)(src);
        f32x4 r1 = *(const f32x4*)(src + kN);
        f32x4 r2 = *(const f32x4*)(src + 2 * kN);
        f32x4 r3 = *(const f32x4*)(src + 3 * kN);
#pragma unroll
        for (int i = 0; i < 4; ++i) {
          f16x4 w;
          w[0] = (_Float16)r0[i]; w[1] = (_Float16)r1[i];
          w[2] = (_Float16)r2[i]; w[3] = (_Float16)r3[i];
          *(f16x4*)(&Ks[m0 + i][c0]) = w;
        }
      }
    }
    {
      const int m0 = 4 * (tid & 15), c0b = 4 * (tid >> 4);
#pragma unroll
      for (int p = 0; p < 4; ++p) {
        const int c0 = c0b + 64 * p;
        const float* src = vb + (size_t)(kv0 + m0) * kCH + c0;
        f32x4 r0 = *(const f32x4*)(src);
        f32x4 r1 = *(const f32x4*)(src + kCH);
        f32x4 r2 = *(const f32x4*)(src + 2 * kCH);
        f32x4 r3 = *(const f32x4*)(src + 3 * kCH);
#pragma unroll
        for (int i = 0; i < 4; ++i) {
          f16x4 w;
          w[0] = (_Float16)r0[i]; w[1] = (_Float16)r1[i];
          w[2] = (_Float16)r2[i]; w[3] = (_Float16)r3[i];
          *(f16x4*)(&Vs[c0 + i][m0]) = w;
        }
      }
    }
    __syncthreads();

    f32x4 sacc[4];
#pragma unroll
    for (int mc = 0; mc < 4; ++mc) sacc[mc] = f32x4{0.f, 0.f, 0.f, 0.f};
#pragma unroll
    for (int mc = 0; mc < 4; ++mc) {
#pragma unroll
      for (int ks = 0; ks < 8; ++ks) {
        f16x8 bf = *(const f16x8*)(&Ks[mc * 16 + s][ks * 32 + qd * 8]);
        sacc[mc] = __builtin_amdgcn_mfma_f32_16x16x32_f16(qf[ks], bf, sacc[mc], 0, 0, 0);
      }
    }
    float pmax[4];
#pragma unroll
    for (int r = 0; r < 4; ++r)
      pmax[r] = fmaxf(fmaxf(sacc[0][r], sacc[1][r]), fmaxf(sacc[2][r], sacc[3][r]));
#pragma unroll
    for (int off = 1; off < 16; off <<= 1) {
#pragma unroll
      for (int r = 0; r < 4; ++r)
        pmax[r] = fmaxf(pmax[r], __shfl_xor(pmax[r], off, 64));
    }
    float corr[4], lsum[4];
#pragma unroll
    for (int r = 0; r < 4; ++r) {
      float mn = fmaxf(m_r[r], SCALE * pmax[r]);
      corr[r] = exp2f((m_r[r] - mn) * LOG2E);
      m_r[r] = mn;
      lsum[r] = 0.f;
    }
#pragma unroll
    for (int mc = 0; mc < 4; ++mc) {
#pragma unroll
      for (int r = 0; r < 4; ++r) {
        float pvf = exp2f((SCALE * sacc[mc][r] - m_r[r]) * LOG2E);
        lsum[r] += pvf;
        Psf[wv][qd * 4 + r][mc * 16 + s] = (_Float16)pvf;
      }
    }
#pragma unroll
    for (int off = 1; off < 16; off <<= 1) {
#pragma unroll
      for (int r = 0; r < 4; ++r) lsum[r] += __shfl_xor(lsum[r], off, 64);
    }
#pragma unroll
    for (int r = 0; r < 4; ++r) l_r[r] = l_r[r] * corr[r] + lsum[r];
    if (s == 0) {
#pragma unroll
      for (int r = 0; r < 4; ++r) red[wv][qd * 4 + r] = corr[r];
    }
    asm volatile("s_waitcnt lgkmcnt(0)" ::: "memory");
    const float sc = red[wv][s];
#pragma unroll
    for (int i = 0; i < 16; ++i) acc[i] *= sc;
#pragma unroll
    for (int ms = 0; ms < 2; ++ms) {
      f16x8 pf = *(const f16x8*)(&Psf[wv][s][ms * 32 + qd * 8]);
#pragma unroll
      for (int ct = 0; ct < 16; ++ct) {
        f16x8 vf = *(const f16x8*)(&Vs[ct * 16 + s][ms * 32 + qd * 8]);
        acc[ct] = __builtin_amdgcn_mfma_f32_16x16x32_f16(vf, pf, acc[ct], 0, 0, 0);
      }
    }
  }
  if (s == 0) {
#pragma unroll
    for (int r = 0; r < 4; ++r) red[wv][qd * 4 + r] = 1.0f / l_r[r];
  }
  asm volatile("s_waitcnt lgkmcnt(0)" ::: "memory");
  const float inv = red[wv][s];
#pragma unroll
  for (int ct = 0; ct < 16; ++ct) {
#pragma unroll
    for (int r = 0; r < 4; ++r) {
      const int c = ct * 16 + qd * 4 + r;
      ob[(size_t)c * kN + n0w + s] = acc[ct][r] * inv;
    }
  }
}

constexpr size_t KT_ELEMS = (size_t)kB * kN * kCH;             // 4M f16
constexpr size_t PACC_ELEMS = (size_t)NSPLIT * kB * kCH * kN;  // 8M f16
constexpr size_t PM_ELEMS = (size_t)kB * kN * NSPLIT;          // 32K f32
constexpr size_t WS_NEED =
    (2 * KT_ELEMS + PACC_ELEMS) * sizeof(_Float16) + 2 * PM_ELEMS * sizeof(float);

}  // namespace

extern "C" void kernel_launch(void* const* d_in, const int* in_sizes, int n_in,
                              void* d_out, int out_size, void* d_ws, size_t ws_size,
                              hipStream_t stream) {
  (void)in_sizes; (void)n_in; (void)out_size;
  const float* k = (const float*)d_in[0];
  const float* q = (const float*)d_in[1];
  const float* v = (const float*)d_in[2];
  float* out = (float*)d_out;

  if (ws_size < WS_NEED) {
    hipLaunchKernelGGL(attn_fwd_fb, dim3(kB * (kN / QBLK_FB)), dim3(256), 0, stream,
                       k, q, v, out);
    return;
  }

  _Float16* kt = (_Float16*)d_ws;
  _Float16* vt = kt + KT_ELEMS;
  _Float16* pacc = vt + KT_ELEMS;
  float* pm = (float*)(pacc + PACC_ELEMS);
  float* pl = pm + PM_ELEMS;

  // kt[b][n][c] = k[b][c][n] (in R=CH, C=N); vt[b][c][n] = v[b][n][c]
  hipLaunchKernelGGL(transpose_cvt2, dim3(kN / 64, kCH / 64, kB), dim3(256), 0, stream,
                     k, kt, kCH, kN);
  hipLaunchKernelGGL(transpose_cvt2, dim3(kCH / 64, kN / 64, kB), dim3(256), 0, stream,
                     v, vt, kN, kCH);
  hipLaunchKernelGGL(attn_part, dim3(kB * (kN / 64) * NSPLIT), dim3(256), 0, stream,
                     kt, q, vt, pacc, pm, pl);
  hipLaunchKernelGGL(attn_merge, dim3(kN / 256, kCH / 16, kB), dim3(256), 0, stream,
                     pacc, pm, pl, out);
}

// Round 6
// 174.105 us; speedup vs baseline: 2.5656x; 1.0267x over previous
//
#include <hip/hip_runtime.h>

namespace {

constexpr int kB = 8;
constexpr int kCH = 256;
constexpr int kN = 2048;
constexpr int NSPLIT = 2;
constexpr int SLICE = kN / NSPLIT;  // 1024 KV positions per block
constexpr int KVC = 64;
constexpr int NWAVE = 8;            // 512-thread blocks
constexpr int QBLK = 128;           // 8 waves x 16 rows
constexpr int PS_STRIDE = KVC + 8;  // 72

constexpr float SCALE = 0.0625f;  // 256^-0.5
constexpr float LOG2E = 1.4426950408889634f;
constexpr float DEFER_THR = 4.0f;  // T13: skip rescale while max growth <= 4

typedef _Float16 f16x8 __attribute__((ext_vector_type(8)));
typedef _Float16 f16x4 __attribute__((ext_vector_type(4)));
typedef float f32x4 __attribute__((ext_vector_type(4)));

__device__ __forceinline__ void gload_lds16(const void* g, void* l) {
  __builtin_amdgcn_global_load_lds(
      (const __attribute__((address_space(1))) void*)g,
      (__attribute__((address_space(3))) void*)l, 16, 0, 0);
}

// ---------------------------------------------------------------------------
// Fused transpose pre-pass (one launch for K and V):
//   z<8 : kt[b][n][c] = f16(k[b][c][n])   (R=kCH, C=kN)
//   z>=8: vt[b][c][n] = f16(v[b][n][c])   (R=kN, C=kCH)
__global__ __launch_bounds__(256) void transpose_both(
    const float* __restrict__ kin, const float* __restrict__ vin,
    _Float16* __restrict__ kt, _Float16* __restrict__ vt) {
  __shared__ _Float16 T[64][72];
  const bool isV = blockIdx.z >= 8;
  const int b = isV ? blockIdx.z - 8 : blockIdx.z;
  const int R = isV ? kN : kCH, C = isV ? kCH : kN;
  const int r0 = (isV ? blockIdx.x : blockIdx.y) * 64;
  const int c0 = (isV ? blockIdx.y : blockIdx.x) * 64;
  const float* in = isV ? vin : kin;
  _Float16* out = isV ? vt : kt;
  const int t = threadIdx.x;

  const float* ib =
      in + (size_t)b * R * C + (size_t)(r0 + (t >> 2)) * C + c0 + (t & 3) * 4;
#pragma unroll
  for (int q = 0; q < 4; ++q) {
    f32x4 v = *(const f32x4*)(ib + q * 16);
    f16x4 w;
    w[0] = (_Float16)v[0]; w[1] = (_Float16)v[1];
    w[2] = (_Float16)v[2]; w[3] = (_Float16)v[3];
    *(f16x4*)(&T[t >> 2][(t & 3) * 4 + q * 16]) = w;
  }
  __syncthreads();
  const int cl = t >> 2, ch = t & 3;
  f16x8 o0, o1;
#pragma unroll
  for (int j = 0; j < 8; ++j) o0[j] = T[ch * 16 + j][cl];
#pragma unroll
  for (int j = 0; j < 8; ++j) o1[j] = T[ch * 16 + 8 + j][cl];
  _Float16* ob = out + (size_t)b * R * C + (size_t)(c0 + cl) * R + r0 + ch * 16;
  *(f16x8*)(ob) = o0;
  *(f16x8*)(ob + 8) = o1;
}

// ---------------------------------------------------------------------------
// Flash-attention partial over a 1024-pos KV slice for 128 Q rows (8 waves).
// Double-buffered LDS staging via global_load_lds (issue next tile BEFORE
// computing current -> L2 latency hides under MFMA+softmax; 1 barrier/chunk).
// Swizzle baked into per-lane GLOBAL source addr; ds_read applies same XOR.
__global__ __launch_bounds__(512, 1) void attn_part(
    const _Float16* __restrict__ kt, const float* __restrict__ qg,
    const _Float16* __restrict__ vt, _Float16* __restrict__ pacc,
    float* __restrict__ pm, float* __restrict__ pl)
{
  __shared__ alignas(16) char KsB[2][64 * 512];   // 2x32KB swizzled [m][cByte]
  __shared__ alignas(16) char VsB[2][256 * 128];  // 2x32KB swizzled [c][mByte]
  __shared__ alignas(16) _Float16 Ps[NWAVE][16][PS_STRIDE];
  __shared__ float red[NWAVE][16];

  const int tid = threadIdx.x;
  const int wv = tid >> 6;
  const int lane = tid & 63;
  const int s = lane & 15;
  const int qd = lane >> 4;
  const int sw = (s & 7) << 4;
  const int qd16 = qd << 4;

  const int bg = blockIdx.x & 15;  // (b,g): slice pinned per-XCD
  const int qt = blockIdx.x >> 4;
  const int b = bg >> 1, g = bg & 1;
  const int n0w = qt * QBLK + wv * 16;
  const int kvb = g * SLICE;

  const char* ktB = (const char*)(kt + (size_t)b * kN * kCH);
  const char* vtB = (const char*)(vt + (size_t)b * kCH * kN);
  const float* qb = qg + (size_t)b * kN * kCH;

  // Q fragments: qf[ks][j] = Q[n0w+s][ks*32 + qd*8 + j]
  f16x8 qf[8];
  {
    const float* qrow = qb + (size_t)(n0w + s) * kCH + qd * 8;
#pragma unroll
    for (int ks = 0; ks < 8; ++ks) {
      f32x4 a = *(const f32x4*)(qrow + ks * 32);
      f32x4 c = *(const f32x4*)(qrow + ks * 32 + 4);
      f16x8 h;
      h[0] = (_Float16)a[0]; h[1] = (_Float16)a[1];
      h[2] = (_Float16)a[2]; h[3] = (_Float16)a[3];
      h[4] = (_Float16)c[0]; h[5] = (_Float16)c[1];
      h[6] = (_Float16)c[2]; h[7] = (_Float16)c[3];
      qf[ks] = h;
    }
  }

  f32x4 acc[16];
#pragma unroll
  for (int i = 0; i < 16; ++i) acc[i] = f32x4{0.f, 0.f, 0.f, 0.f};
  float m_r[4] = {-1e30f, -1e30f, -1e30f, -1e30f};
  float l_r[4] = {0.f, 0.f, 0.f, 0.f};

  // stage one 64-pos tile into buffer bf (8 issues/thread, 16B each)
  auto STAGE = [&](int bf, int kv0) {
    const char* kSrc = ktB + (size_t)kv0 * 512;  // row m: 512B
    const char* vSrc = vtB + (size_t)kv0 * 2;    // row c: stride 4096B
    char* kDst = KsB[bf];
    char* vDst = VsB[bf];
#pragma unroll
    for (int ii = 0; ii < 4; ++ii) {
      const int j = ii * 8 + wv;  // 32 x 1KB segments
      const int L = j * 1024 + lane * 16;
      {
        const int row = L >> 9, cb = L & 511;
        gload_lds16(kSrc + (size_t)(row << 9) + (cb ^ ((row & 7) << 4)),
                    kDst + j * 1024);
      }
      {
        const int row = L >> 7, cb = L & 127;
        gload_lds16(vSrc + (size_t)row * 4096 + (cb ^ ((row & 7) << 4)),
                    vDst + j * 1024);
      }
    }
  };

  constexpr int NCHUNK = SLICE / KVC;  // 16
  STAGE(0, kvb);
  __syncthreads();  // vmcnt(0) drain: buf0 ready

  for (int ck = 0; ck < NCHUNK; ++ck) {
    const int cur = ck & 1;
    if (ck + 1 < NCHUNK) STAGE(cur ^ 1, kvb + (ck + 1) * KVC);  // prefetch

    // ---- QK^T: S[16n x 64m], A=Q(reg), B=K(LDS swizzled)
    f32x4 sacc[4];
#pragma unroll
    for (int mc = 0; mc < 4; ++mc) sacc[mc] = f32x4{0.f, 0.f, 0.f, 0.f};
#pragma unroll
    for (int mc = 0; mc < 4; ++mc) {
      const char* kr = KsB[cur] + (mc * 16 + s) * 512;
#pragma unroll
      for (int ks = 0; ks < 8; ++ks) {
        f16x8 bf = *(const f16x8*)(kr + (((ks << 6) | qd16) ^ sw));
        sacc[mc] = __builtin_amdgcn_mfma_f32_16x16x32_f16(qf[ks], bf, sacc[mc], 0, 0, 0);
      }
    }

    // ---- online softmax (rows qd*4+r, cols mc*16+s)
    float pmax[4];
#pragma unroll
    for (int r = 0; r < 4; ++r)
      pmax[r] = fmaxf(fmaxf(sacc[0][r], sacc[1][r]), fmaxf(sacc[2][r], sacc[3][r]));
#pragma unroll
    for (int off = 1; off < 16; off <<= 1) {
#pragma unroll
      for (int r = 0; r < 4; ++r)
        pmax[r] = fmaxf(pmax[r], __shfl_xor(pmax[r], off, 64));
    }

    // T13 defer-rescale: only pay the rescale when some row's max grew > THR
    bool grow = false;
#pragma unroll
    for (int r = 0; r < 4; ++r)
      grow = grow || (SCALE * pmax[r] > m_r[r] + DEFER_THR);
    if (__any((int)grow)) {
      float corr[4];
#pragma unroll
      for (int r = 0; r < 4; ++r) {
        float mn = fmaxf(m_r[r], SCALE * pmax[r]);
        corr[r] = exp2f((m_r[r] - mn) * LOG2E);
        m_r[r] = mn;
        l_r[r] *= corr[r];
      }
      if (s == 0) {
#pragma unroll
        for (int r = 0; r < 4; ++r) red[wv][qd * 4 + r] = corr[r];
      }
      asm volatile("s_waitcnt lgkmcnt(0)" ::: "memory");
      const float sc = red[wv][s];
#pragma unroll
      for (int i = 0; i < 16; ++i) acc[i] *= sc;
    }

    float lsum[4] = {0.f, 0.f, 0.f, 0.f};
#pragma unroll
    for (int mc = 0; mc < 4; ++mc) {
#pragma unroll
      for (int r = 0; r < 4; ++r) {
        float pvf = exp2f((SCALE * sacc[mc][r] - m_r[r]) * LOG2E);
        lsum[r] += pvf;
        Ps[wv][qd * 4 + r][mc * 16 + s] = (_Float16)pvf;
      }
    }
#pragma unroll
    for (int off = 1; off < 16; off <<= 1) {
#pragma unroll
      for (int r = 0; r < 4; ++r) lsum[r] += __shfl_xor(lsum[r], off, 64);
    }
#pragma unroll
    for (int r = 0; r < 4; ++r) l_r[r] += lsum[r];

    asm volatile("s_waitcnt lgkmcnt(0)" ::: "memory");  // Ps visible wave-wide

    // ---- PV: O^T += V^T @ P^T  (A=V from LDS swizzled, B=P from LDS)
#pragma unroll
    for (int ms = 0; ms < 2; ++ms) {
      f16x8 pf = *(const f16x8*)(&Ps[wv][s][ms * 32 + qd * 8]);
#pragma unroll
      for (int ct = 0; ct < 16; ++ct) {
        const char* vr = VsB[cur] + (ct * 16 + s) * 128;
        f16x8 vf = *(const f16x8*)(vr + (((ms << 6) | qd16) ^ sw));
        acc[ct] = __builtin_amdgcn_mfma_f32_16x16x32_f16(vf, pf, acc[ct], 0, 0, 0);
      }
    }
    __syncthreads();  // drains prefetch (vmcnt0) + guards buffer reuse
  }

  // ---- store partials (unnormalized; pm holds the possibly-stale m, exact)
  _Float16* pb = pacc + (size_t)(b * NSPLIT + g) * kCH * kN;
#pragma unroll
  for (int ct = 0; ct < 16; ++ct) {
#pragma unroll
    for (int r = 0; r < 4; ++r) {
      const int c = ct * 16 + qd * 4 + r;
      pb[(size_t)c * kN + n0w + s] = (_Float16)acc[ct][r];
    }
  }
  if (s == 0) {
#pragma unroll
    for (int r = 0; r < 4; ++r) {
      const int n = n0w + qd * 4 + r;
      pm[((size_t)b * kN + n) * NSPLIT + g] = m_r[r];
      pl[((size_t)b * kN + n) * NSPLIT + g] = l_r[r];
    }
  }
}

// ---------------------------------------------------------------------------
// Merge: out[b][c][n] = sum_g a_g * pacc[b][g][c][n] / L.
__global__ void attn_merge(const _Float16* __restrict__ pacc,
                           const float* __restrict__ pm,
                           const float* __restrict__ pl,
                           float* __restrict__ out) {
  const int b = blockIdx.z;
  const int c = blockIdx.y * 16 + (threadIdx.x >> 4);
  const int nn0 = blockIdx.x * 256 + (threadIdx.x & 15) * 16;

  f16x8 dA[NSPLIT], dB[NSPLIT];
#pragma unroll
  for (int g = 0; g < NSPLIT; ++g) {
    const _Float16* p = pacc + ((size_t)(b * NSPLIT + g) * kCH + c) * kN + nn0;
    dA[g] = *(const f16x8*)(p);
    dB[g] = *(const f16x8*)(p + 8);
  }
  float mv[32], lv[32];
  const float* pmB = pm + ((size_t)b * kN + nn0) * NSPLIT;
  const float* plB = pl + ((size_t)b * kN + nn0) * NSPLIT;
#pragma unroll
  for (int q = 0; q < 8; ++q) {
    *(f32x4*)&mv[q * 4] = *(const f32x4*)(pmB + q * 4);
    *(f32x4*)&lv[q * 4] = *(const f32x4*)(plB + q * 4);
  }
  float res[16];
#pragma unroll
  for (int j = 0; j < 16; ++j) {
    float m0 = mv[2 * j], m1 = mv[2 * j + 1];
    float M = fmaxf(m0, m1);
    float a0 = exp2f((m0 - M) * LOG2E);
    float a1 = exp2f((m1 - M) * LOG2E);
    float L = a0 * lv[2 * j] + a1 * lv[2 * j + 1];
    float v = (j < 8) ? a0 * (float)dA[0][j] + a1 * (float)dA[1][j]
                      : a0 * (float)dB[0][j - 8] + a1 * (float)dB[1][j - 8];
    res[j] = v / L;
  }
  float* o = out + ((size_t)b * kCH + c) * kN + nn0;
#pragma unroll
  for (int j = 0; j < 4; ++j)
    *(f32x4*)(o + j * 4) = f32x4{res[j * 4], res[j * 4 + 1], res[j * 4 + 2], res[j * 4 + 3]};
}

// ---------------------------------------------------------------------------
// Round-1 fallback (used only if ws_size is too small). Verified correct.
constexpr int QBLK_FB = 64;
constexpr int KVBLK_FB = 64;
constexpr int KS_STRIDE_FB = kCH + 8;
constexpr int VS_STRIDE_FB = KVBLK_FB + 8;

__global__ __launch_bounds__(256, 1) void attn_fwd_fb(
    const float* __restrict__ kg, const float* __restrict__ qg,
    const float* __restrict__ vg, float* __restrict__ og)
{
  __shared__ alignas(16) _Float16 Ks[KVBLK_FB][KS_STRIDE_FB];
  __shared__ alignas(16) _Float16 Vs[kCH][VS_STRIDE_FB];
  __shared__ alignas(16) _Float16 Psf[4][16][VS_STRIDE_FB];
  __shared__ float red[4][16];

  const int tid = threadIdx.x;
  const int wv = tid >> 6, lane = tid & 63, s = lane & 15, qd = lane >> 4;
  const int b = blockIdx.x & 7, qt = blockIdx.x >> 3;
  const int n0w = qt * QBLK_FB + wv * 16;
  const float* kb = kg + (size_t)b * kCH * kN;
  const float* qb = qg + (size_t)b * kN * kCH;
  const float* vb = vg + (size_t)b * kN * kCH;
  float* ob = og + (size_t)b * kCH * kN;

  f16x8 qf[8];
  {
    const float* qrow = qb + (size_t)(n0w + s) * kCH + qd * 8;
#pragma unroll
    for (int ks = 0; ks < 8; ++ks) {
      f32x4 a = *(const f32x4*)(qrow + ks * 32);
      f32x4 c = *(const f32x4*)(qrow + ks * 32 + 4);
      f16x8 h;
      h[0] = (_Float16)a[0]; h[1] = (_Float16)a[1];
      h[2] = (_Float16)a[2]; h[3] = (_Float16)a[3];
      h[4] = (_Float16)c[0]; h[5] = (_Float16)c[1];
      h[6] = (_Float16)c[2]; h[7] = (_Float16)c[3];
      qf[ks] = h;
    }
  }
  f32x4 acc[16];
#pragma unroll
  for (int i = 0; i < 16; ++i) acc[i] = f32x4{0.f, 0.f, 0.f, 0.f};
  float m_r[4] = {-1e30f, -1e30f, -1e30f, -1e30f};
  float l_r[4] = {0.f, 0.f, 0.f, 0.f};

  for (int kv0 = 0; kv0 < kN; kv0 += KVBLK_FB) {
    __syncthreads();
    {
      const int m0 = 4 * (tid >> 4), c0b = 4 * (tid & 15);
#pragma unroll
      for (int p = 0; p < 4; ++p) {
        const int c0 = c0b + 64 * p;
        const float* src = kb + (size_t)c0 * kN + kv0 + m0;
        f32x4 r0 = *(const f32x4*)(src);
        f32x4 r1 = *(const f32x4*)(src + kN);
        f32x4 r2 = *(const f32x4*)(src + 2 * kN);
        f32x4 r3 = *(const f32x4*)(src + 3 * kN);
#pragma unroll
        for (int i = 0; i < 4; ++i) {
          f16x4 w;
          w[0] = (_Float16)r0[i]; w[1] = (_Float16)r1[i];
          w[2] = (_Float16)r2[i]; w[3] = (_Float16)r3[i];
          *(f16x4*)(&Ks[m0 + i][c0]) = w;
        }
      }
    }
    {
      const int m0 = 4 * (tid & 15), c0b = 4 * (tid >> 4);
#pragma unroll
      for (int p = 0; p < 4; ++p) {
        const int c0 = c0b + 64 * p;
        const float* src = vb + (size_t)(kv0 + m0) * kCH + c0;
        f32x4 r0 = *(const f32x4*)(src);
        f32x4 r1 = *(const f32x4*)(src + kCH);
        f32x4 r2 = *(const f32x4*)(src + 2 * kCH);
        f32x4 r3 = *(const f32x4*)(src + 3 * kCH);
#pragma unroll
        for (int i = 0; i < 4; ++i) {
          f16x4 w;
          w[0] = (_Float16)r0[i]; w[1] = (_Float16)r1[i];
          w[2] = (_Float16)r2[i]; w[3] = (_Float16)r3[i];
          *(f16x4*)(&Vs[c0 + i][m0]) = w;
        }
      }
    }
    __syncthreads();

    f32x4 sacc[4];
#pragma unroll
    for (int mc = 0; mc < 4; ++mc) sacc[mc] = f32x4{0.f, 0.f, 0.f, 0.f};
#pragma unroll
    for (int mc = 0; mc < 4; ++mc) {
#pragma unroll
      for (int ks = 0; ks < 8; ++ks) {
        f16x8 bf = *(const f16x8*)(&Ks[mc * 16 + s][ks * 32 + qd * 8]);
        sacc[mc] = __builtin_amdgcn_mfma_f32_16x16x32_f16(qf[ks], bf, sacc[mc], 0, 0, 0);
      }
    }
    float pmax[4];
#pragma unroll
    for (int r = 0; r < 4; ++r)
      pmax[r] = fmaxf(fmaxf(sacc[0][r], sacc[1][r]), fmaxf(sacc[2][r], sacc[3][r]));
#pragma unroll
    for (int off = 1; off < 16; off <<= 1) {
#pragma unroll
      for (int r = 0; r < 4; ++r)
        pmax[r] = fmaxf(pmax[r], __shfl_xor(pmax[r], off, 64));
    }
    float corr[4], lsum[4];
#pragma unroll
    for (int r = 0; r < 4; ++r) {
      float mn = fmaxf(m_r[r], SCALE * pmax[r]);
      corr[r] = exp2f((m_r[r] - mn) * LOG2E);
      m_r[r] = mn;
      lsum[r] = 0.f;
    }
#pragma unroll
    for (int mc = 0; mc < 4; ++mc) {
#pragma unroll
      for (int r = 0; r < 4; ++r) {
        float pvf = exp2f((SCALE * sacc[mc][r] - m_r[r]) * LOG2E);
        lsum[r] += pvf;
        Psf[wv][qd * 4 + r][mc * 16 + s] = (_Float16)pvf;
      }
    }
#pragma unroll
    for (int off = 1; off < 16; off <<= 1) {
#pragma unroll
      for (int r = 0; r < 4; ++r) lsum[r] += __shfl_xor(lsum[r], off, 64);
    }
#pragma unroll
    for (int r = 0; r < 4; ++r) l_r[r] = l_r[r] * corr[r] + lsum[r];
    if (s == 0) {
#pragma unroll
      for (int r = 0; r < 4; ++r) red[wv][qd * 4 + r] = corr[r];
    }
    asm volatile("s_waitcnt lgkmcnt(0)" ::: "memory");
    const float sc = red[wv][s];
#pragma unroll
    for (int i = 0; i < 16; ++i) acc[i] *= sc;
#pragma unroll
    for (int ms = 0; ms < 2; ++ms) {
      f16x8 pf = *(const f16x8*)(&Psf[wv][s][ms * 32 + qd * 8]);
#pragma unroll
      for (int ct = 0; ct < 16; ++ct) {
        f16x8 vf = *(const f16x8*)(&Vs[ct * 16 + s][ms * 32 + qd * 8]);
        acc[ct] = __builtin_amdgcn_mfma_f32_16x16x32_f16(vf, pf, acc[ct], 0, 0, 0);
      }
    }
  }
  if (s == 0) {
#pragma unroll
    for (int r = 0; r < 4; ++r) red[wv][qd * 4 + r] = 1.0f / l_r[r];
  }
  asm volatile("s_waitcnt lgkmcnt(0)" ::: "memory");
  const float inv = red[wv][s];
#pragma unroll
  for (int ct = 0; ct < 16; ++ct) {
#pragma unroll
    for (int r = 0; r < 4; ++r) {
      const int c = ct * 16 + qd * 4 + r;
      ob[(size_t)c * kN + n0w + s] = acc[ct][r] * inv;
    }
  }
}

constexpr size_t KT_ELEMS = (size_t)kB * kN * kCH;             // 4M f16
constexpr size_t PACC_ELEMS = (size_t)NSPLIT * kB * kCH * kN;  // 8M f16
constexpr size_t PM_ELEMS = (size_t)kB * kN * NSPLIT;          // 32K f32
constexpr size_t WS_NEED =
    (2 * KT_ELEMS + PACC_ELEMS) * sizeof(_Float16) + 2 * PM_ELEMS * sizeof(float);

}  // namespace

extern "C" void kernel_launch(void* const* d_in, const int* in_sizes, int n_in,
                              void* d_out, int out_size, void* d_ws, size_t ws_size,
                              hipStream_t stream) {
  (void)in_sizes; (void)n_in; (void)out_size;
  const float* k = (const float*)d_in[0];
  const float* q = (const float*)d_in[1];
  const float* v = (const float*)d_in[2];
  float* out = (float*)d_out;

  if (ws_size < WS_NEED) {
    hipLaunchKernelGGL(attn_fwd_fb, dim3(kB * (kN / QBLK_FB)), dim3(256), 0, stream,
                       k, q, v, out);
    return;
  }

  _Float16* kt = (_Float16*)d_ws;
  _Float16* vt = kt + KT_ELEMS;
  _Float16* pacc = vt + KT_ELEMS;
  float* pm = (float*)(pacc + PACC_ELEMS);
  float* pl = pm + PM_ELEMS;

  // K part needs grid (kN/64, kCH/64); V part uses swapped roles of (x,y).
  hipLaunchKernelGGL(transpose_both, dim3(kN / 64, kCH / 64, 16), dim3(256), 0,
                     stream, k, v, kt, vt);
  hipLaunchKernelGGL(attn_part, dim3(kB * (kN / QBLK) * NSPLIT), dim3(512), 0,
                     stream, kt, q, vt, pacc, pm, pl);
  hipLaunchKernelGGL(attn_merge, dim3(kN / 256, kCH / 16, kB), dim3(256), 0, stream,
                     pacc, pm, pl, out);
}